// Round 1
// baseline (21705.844 us; speedup 1.0000x reference)
//
#include <hip/hip_runtime.h>
#include <math.h>

#define BB 256
#define TT 100
#define DD 784
#define HH 128
#define NEGV -1e9f

struct Params {
  const float *x, *gum;
  const float *W1, *b1, *W2, *b2, *W3, *b3, *W4, *b4;
  const float *Wf2, *bf2, *Wg1, *bg1, *Wg2, *bg2;
  const float *Wih, *Whh, *bih, *bhh;
  unsigned* bar;   // 256 flags, 128B apart (32 KB)
  float* wsf;      // float workspace after flags
  int* ilist;      // [256][128] sampled-pixel indices
  float* out;      // [B,10,T]
};

__device__ __forceinline__ float leaky_(float v) { return v > 0.f ? v : 0.2f * v; }
__device__ __forceinline__ float sigm_(float v)  { return 1.f / (1.f + expf(-v)); }

// 16-WG group barrier: monotonic per-WG flags (no RMW contention).
// Producer: __threadfence (agent release -> L2 writeback) + agent-scope flag store.
// Consumer: wave0 polls all 16 group flags (one lane each), then __threadfence
// (agent acquire -> L2 invalidate) so post-barrier reads see remote XCD writes.
__device__ __forceinline__ void group_barrier(unsigned* bar, int rb, int wg, int tid, int barn) {
  __syncthreads();
  if (tid < 64) {
    if (tid == 0) {
      __threadfence();
      __hip_atomic_store(bar + wg * 32, (unsigned)barn, __ATOMIC_RELEASE, __HIP_MEMORY_SCOPE_AGENT);
    }
    const unsigned tgt = (unsigned)barn;
    unsigned long long spin = 0;
    for (;;) {
      unsigned v = tgt;
      if (tid < 16)
        v = __hip_atomic_load(bar + (rb * 16 + tid) * 32, __ATOMIC_RELAXED, __HIP_MEMORY_SCOPE_AGENT);
      if ((__ballot(v >= tgt) & 0xFFFFull) == 0xFFFFull) break;
      if (++spin > (1ull << 23)) break;  // safety valve (never hit in practice)
    }
    __threadfence();
  }
  __syncthreads();
}

// Dense layer for 16 rows (staged in LDS) x CWG output cols per WG, float4 weight
// loads, K split across threads with LDS partial reduction.
template <int K, int CTOT, int CWG, bool LEAKY>
__device__ __forceinline__ void dense_qsplit(const float* sin, const float* W,
                                             const float* bias, float* outbuf,
                                             int row0, int cb, float* spart, int tid) {
  constexpr int NQ = CWG / 4;      // quads per WG
  constexpr int KC = 16 / NQ;      // K chunks
  constexpr int KLEN = K / KC;
  const int bl = tid >> 4;
  const int rem = tid & 15;
  const int kc = rem / NQ;
  const int qd = rem % NQ;
  const int c0 = cb * CWG + qd * 4;
  float4 acc = make_float4(0.f, 0.f, 0.f, 0.f);
  const float* ip = sin + bl * K;
  const float* wp = W + c0;
#pragma unroll 4
  for (int k = kc * KLEN; k < kc * KLEN + KLEN; ++k) {
    const float v = ip[k];
    const float4 w4 = *reinterpret_cast<const float4*>(wp + (size_t)k * CTOT);
    acc.x += v * w4.x; acc.y += v * w4.y; acc.z += v * w4.z; acc.w += v * w4.w;
  }
  *reinterpret_cast<float4*>(spart + ((bl * NQ + qd) * KC + kc) * 4) = acc;
  __syncthreads();
  if (tid < 16 * CWG) {
    const int rbl = (CWG == 16) ? (tid >> 4) : (tid >> 3);
    const int u = tid & (CWG - 1);
    const int qq = u >> 2, ii = u & 3;
    float s = 0.f;
#pragma unroll
    for (int k2 = 0; k2 < KC; ++k2) s += spart[((rbl * NQ + qq) * KC + k2) * 4 + ii];
    s += bias[cb * CWG + u];
    if (LEAKY) s = leaky_(s);
    outbuf[(size_t)(row0 + rbl) * CTOT + cb * CWG + u] = s;
  }
}

__global__ __launch_bounds__(256, 1) void net_kernel(Params p) {
  __shared__ float smem[16 * DD];   // 50176 B staging
  __shared__ float spart[1024];
  __shared__ float rv[256];
  __shared__ int   ri[256];

  const int tid = threadIdx.x;
  const int wg = blockIdx.x;
  const int rb = wg >> 4;    // row group (16 rows)
  const int cb = wg & 15;    // column-slice id within group
  const int row0 = rb * 16;

  float* h0  = p.wsf;
  float* h1  = h0 + BB * HH;
  float* cst = h1 + BB * HH;
  float* aa  = cst + BB * HH;      // lin (LSTM input) = previous step's a
  float* mem = aa + BB * HH;       // [B,784] sampled mask
  float* g1b = mem + BB * DD;      // [B,256]
  float* prt = g1b + BB * 256;     // [B,784] perturbed logits
  float* t1b = prt + BB * DD;      // [B,784]
  float* t2b = t1b + BB * DD;      // [B,256]
  float* t3b = t2b + BB * 256;     // [B,128]

  int barn = 0;

  for (int t = 0; t < TT; ++t) {
    float* hprev = (t & 1) ? h1 : h0;
    float* hnew  = (t & 1) ? h0 : h1;

    // ===== ph1: LSTM gates -> h,c ; plus s(t-1) = a @ Wf2 =====
    for (int i = tid; i < 16 * HH; i += 256) {
      const int r = i >> 7, k = i & (HH - 1);
      smem[i]           = aa[(size_t)(row0 + r) * HH + k];
      smem[16 * HH + i] = hprev[(size_t)(row0 + r) * HH + k];
    }
    __syncthreads();
    float* sgate = smem + 2 * 16 * HH;  // 512 floats
    if (tid < 128) {
      const int bl = tid >> 3;
      const int q  = (tid >> 1) & 3;   // gate i,f,g,o
      const int cq = tid & 1;
      const int col4 = cb * 8 + cq * 4;
      const float* sa = smem + bl * HH;
      const float* sh = smem + 16 * HH + bl * HH;
      const float* wi = p.Wih + q * 128 + col4;
      const float* wh = p.Whh + q * 128 + col4;
      float4 acc = make_float4(0.f, 0.f, 0.f, 0.f);
#pragma unroll 2
      for (int k = 0; k < HH; ++k) {
        const float av = sa[k], hv = sh[k];
        const float4 wiv = *reinterpret_cast<const float4*>(wi + (size_t)k * 512);
        const float4 whv = *reinterpret_cast<const float4*>(wh + (size_t)k * 512);
        acc.x += av * wiv.x + hv * whv.x;
        acc.y += av * wiv.y + hv * whv.y;
        acc.z += av * wiv.z + hv * whv.z;
        acc.w += av * wiv.w + hv * whv.w;
      }
      const int bc = q * 128 + col4;
      acc.x += p.bih[bc]     + p.bhh[bc];
      acc.y += p.bih[bc + 1] + p.bhh[bc + 1];
      acc.z += p.bih[bc + 2] + p.bhh[bc + 2];
      acc.w += p.bih[bc + 3] + p.bhh[bc + 3];
      *reinterpret_cast<float4*>(sgate + ((q * 16 + bl) * 8 + cq * 4)) = acc;
    }
    if (cb == 15 && t > 0 && tid >= 96) {  // s(t-1), overlapped with gate calc
      const int u = tid - 96;
      const int bl = u / 10;
      const int sc = u - bl * 10;
      const float* sa = smem + bl * HH;
      const float* w = p.Wf2 + (size_t)(t - 1) * HH * 10 + sc;
      float acc = p.bf2[(t - 1) * 10 + sc];
#pragma unroll 4
      for (int k = 0; k < HH; ++k) acc += sa[k] * w[k * 10];
      p.out[(size_t)(row0 + bl) * 1000 + sc * 100 + (t - 1)] = acc;
    }
    __syncthreads();
    if (tid < 128) {
      const int bl = tid >> 3, jl = tid & 7;
      const int col = cb * 8 + jl;
      const int b = row0 + bl;
      const float gi = sgate[(0 * 16 + bl) * 8 + jl];
      const float gf = sgate[(1 * 16 + bl) * 8 + jl];
      const float gg = sgate[(2 * 16 + bl) * 8 + jl];
      const float go = sgate[(3 * 16 + bl) * 8 + jl];
      const float cv = cst[(size_t)b * HH + col];
      const float cn = sigm_(gf) * cv + sigm_(gi) * tanhf(gg);
      const float hn = sigm_(go) * tanhf(cn);
      cst[(size_t)b * HH + col]  = cn;
      hnew[(size_t)b * HH + col] = hn;
    }
    group_barrier(p.bar, rb, wg, tid, ++barn);

    // ===== ph2: g1 = leaky(h @ Wg1 + bg1) =====
    for (int i = tid; i < 16 * HH; i += 256) {
      const int r = i >> 7, k = i & (HH - 1);
      smem[i] = hnew[(size_t)(row0 + r) * HH + k];
    }
    __syncthreads();
    dense_qsplit<HH, 256, 16, true>(smem, p.Wg1 + (size_t)t * HH * 256,
                                    p.bg1 + (size_t)t * 256, g1b, row0, cb, spart, tid);
    group_barrier(p.bar, rb, wg, tid, ++barn);

    // ===== ph3: pert = mem>0 ? NEG : g1 @ Wg2 + bg2 + gumbel =====
    for (int i = tid; i < 16 * 256; i += 256) {
      const int r = i >> 8, k = i & 255;
      smem[i] = g1b[(size_t)(row0 + r) * 256 + k];
    }
    __syncthreads();
    {
      const int bl = tid >> 4, cl = tid & 15;
      int q = -1;                                   // quad id 0..195
      if (cl < 12) q = cb * 12 + cl;
      else if (cl == 12 && cb < 4) q = 192 + cb;
      if (q >= 0) {
        const int b = row0 + bl;
        const int c0 = q * 4;
        const float* sg = smem + bl * 256;
        const float* w = p.Wg2 + (size_t)t * 256 * DD + c0;
        float4 acc = *reinterpret_cast<const float4*>(p.bg2 + (size_t)t * DD + c0);
#pragma unroll 4
        for (int k = 0; k < 256; ++k) {
          const float gv = sg[k];
          const float4 w4 = *reinterpret_cast<const float4*>(w + (size_t)k * DD);
          acc.x += gv * w4.x; acc.y += gv * w4.y; acc.z += gv * w4.z; acc.w += gv * w4.w;
        }
        const float4 g4 = *reinterpret_cast<const float4*>(p.gum + ((size_t)t * BB + b) * DD + c0);
        const float4 m4 = *reinterpret_cast<const float4*>(mem + (size_t)b * DD + c0);
        float4 r4;
        r4.x = m4.x > 0.f ? NEGV : acc.x + g4.x;
        r4.y = m4.y > 0.f ? NEGV : acc.y + g4.y;
        r4.z = m4.z > 0.f ? NEGV : acc.z + g4.z;
        r4.w = m4.w > 0.f ? NEGV : acc.w + g4.w;
        *reinterpret_cast<float4*>(prt + (size_t)b * DD + c0) = r4;
      }
    }
    group_barrier(p.bar, rb, wg, tid, ++barn);

    // ===== ph4: per-row argmax (first-index ties), mem/ilist update =====
    {
      const int b = row0 + cb;   // one row per WG within the group
      const float* pr = prt + (size_t)b * DD;
      float bv = -1e30f; int bi = 0;
      for (int d = tid; d < DD; d += 256) {
        const float v = pr[d];
        if (v > bv) { bv = v; bi = d; }
      }
      rv[tid] = bv; ri[tid] = bi;
      __syncthreads();
      for (int s = 128; s > 0; s >>= 1) {
        if (tid < s) {
          const float v2 = rv[tid + s]; const int i2 = ri[tid + s];
          if (v2 > rv[tid] || (v2 == rv[tid] && i2 < ri[tid])) { rv[tid] = v2; ri[tid] = i2; }
        }
        __syncthreads();
      }
      if (tid == 0) {
        const int j = ri[0];
        mem[(size_t)b * DD + j] = 1.f;
        p.ilist[b * 128 + t] = j;
      }
    }
    group_barrier(p.bar, rb, wg, tid, ++barn);

    // ===== ph5: t1 = leaky(y @ W1 + b1), SPARSE over t+1 sampled pixels =====
    {
      int* sidx = reinterpret_cast<int*>(smem);
      float* sval = smem + 1664;
      const int nnz = t + 1;
      for (int i = tid; i < 16 * nnz; i += 256) {
        const int r = i / nnz, n = i - r * nnz;
        const int kk = p.ilist[(row0 + r) * 128 + n];
        sidx[r * 100 + n] = kk;
        sval[r * 100 + n] = p.x[(size_t)(row0 + r) * DD + kk];
      }
      __syncthreads();
      const int bl = tid >> 4, cl = tid & 15;
      int q = -1;
      if (cl < 12) q = cb * 12 + cl;
      else if (cl == 12 && cb < 4) q = 192 + cb;
      if (q >= 0) {
        const int c0 = q * 4;
        const float* w = p.W1 + (size_t)t * DD * DD + c0;
        float4 acc = *reinterpret_cast<const float4*>(p.b1 + (size_t)t * DD + c0);
        const int* si = sidx + bl * 100;
        const float* sv = sval + bl * 100;
        for (int n = 0; n < nnz; ++n) {
          const float yv = sv[n];
          const float4 w4 = *reinterpret_cast<const float4*>(w + (size_t)si[n] * DD);
          acc.x += yv * w4.x; acc.y += yv * w4.y; acc.z += yv * w4.z; acc.w += yv * w4.w;
        }
        float4 o4;
        o4.x = leaky_(acc.x); o4.y = leaky_(acc.y); o4.z = leaky_(acc.z); o4.w = leaky_(acc.w);
        *reinterpret_cast<float4*>(t1b + (size_t)(row0 + bl) * DD + c0) = o4;
      }
    }
    group_barrier(p.bar, rb, wg, tid, ++barn);

    // ===== ph6: t2 = leaky(t1 @ W2 + b2) =====
    for (int i = tid; i < 16 * DD; i += 256) {
      const int r = i / DD, k = i - r * DD;
      smem[i] = t1b[(size_t)(row0 + r) * DD + k];
    }
    __syncthreads();
    dense_qsplit<DD, 256, 16, true>(smem, p.W2 + (size_t)t * DD * 256,
                                    p.b2 + (size_t)t * 256, t2b, row0, cb, spart, tid);
    group_barrier(p.bar, rb, wg, tid, ++barn);

    // ===== ph7: t3 = leaky(t2 @ W3 + b3) =====
    for (int i = tid; i < 16 * 256; i += 256) {
      const int r = i >> 8, k = i & 255;
      smem[i] = t2b[(size_t)(row0 + r) * 256 + k];
    }
    __syncthreads();
    dense_qsplit<256, HH, 8, true>(smem, p.W3 + (size_t)t * 256 * HH,
                                   p.b3 + (size_t)t * HH, t3b, row0, cb, spart, tid);
    group_barrier(p.bar, rb, wg, tid, ++barn);

    // ===== ph8: a = leaky(t3 @ W4 + b4) =====
    for (int i = tid; i < 16 * HH; i += 256) {
      const int r = i >> 7, k = i & (HH - 1);
      smem[i] = t3b[(size_t)(row0 + r) * HH + k];
    }
    __syncthreads();
    dense_qsplit<HH, HH, 8, true>(smem, p.W4 + (size_t)t * HH * HH,
                                  p.b4 + (size_t)t * HH, aa, row0, cb, spart, tid);
    group_barrier(p.bar, rb, wg, tid, ++barn);
  }

  // ===== final s(99) =====
  if (cb == 15) {
    for (int i = tid; i < 16 * HH; i += 256) {
      const int r = i >> 7, k = i & (HH - 1);
      smem[i] = aa[(size_t)(row0 + r) * HH + k];
    }
    __syncthreads();
    if (tid >= 96) {
      const int u = tid - 96;
      const int bl = u / 10;
      const int sc = u - bl * 10;
      const float* sa = smem + bl * HH;
      const float* w = p.Wf2 + (size_t)99 * HH * 10 + sc;
      float acc = p.bf2[99 * 10 + sc];
#pragma unroll 4
      for (int k = 0; k < HH; ++k) acc += sa[k] * w[k * 10];
      p.out[(size_t)(row0 + bl) * 1000 + sc * 100 + 99] = acc;
    }
  }
}

extern "C" void kernel_launch(void* const* d_in, const int* in_sizes, int n_in,
                              void* d_out, int out_size, void* d_ws, size_t ws_size,
                              hipStream_t stream) {
  (void)in_sizes; (void)n_in; (void)out_size; (void)ws_size;
  Params p;
  p.x   = (const float*)d_in[0];
  p.gum = (const float*)d_in[1];
  p.W1  = (const float*)d_in[2];  p.b1  = (const float*)d_in[3];
  p.W2  = (const float*)d_in[4];  p.b2  = (const float*)d_in[5];
  p.W3  = (const float*)d_in[6];  p.b3  = (const float*)d_in[7];
  p.W4  = (const float*)d_in[8];  p.b4  = (const float*)d_in[9];
  p.Wf2 = (const float*)d_in[10]; p.bf2 = (const float*)d_in[11];
  p.Wg1 = (const float*)d_in[12]; p.bg1 = (const float*)d_in[13];
  p.Wg2 = (const float*)d_in[14]; p.bg2 = (const float*)d_in[15];
  p.Wih = (const float*)d_in[16]; p.Whh = (const float*)d_in[17];
  p.bih = (const float*)d_in[18]; p.bhh = (const float*)d_in[19];
  p.bar = (unsigned*)d_ws;
  p.wsf = (float*)((char*)d_ws + 32768);
  p.ilist = (int*)(p.wsf + 897024);
  p.out = (float*)d_out;
  // zero: barrier flags (32KB) + h0,h1,c,a (4*128KB) + mem (784KB)
  hipMemsetAsync(d_ws, 0, 1359872, stream);
  hipLaunchKernelGGL(net_kernel, dim3(256), dim3(256), 0, stream, p);
}